// Round 1
// baseline (452.361 us; speedup 1.0000x reference)
//
#include <hip/hip_runtime.h>
#include <math.h>

#define TPB 256
#define MAXBLOCKS 8192

__device__ __forceinline__ float fsqrt_(float x){ return __builtin_amdgcn_sqrtf(x); }
__device__ __forceinline__ float frcp_ (float x){ return __builtin_amdgcn_rcpf(x); }
__device__ __forceinline__ float frsq_ (float x){ return __builtin_amdgcn_rsqf(x); }
// fast pow for x>=0 (x==0 -> 0, no NaN: log(0)=-inf, exp(-inf)=0)
__device__ __forceinline__ float fpow_(float x, float y){ return __expf(y * __logf(x)); }

__device__ __forceinline__ float srgb_lin(float c){
    float p = fpow_((c + 0.055f) * (1.0f/1.055f), 2.4f);
    return (c > 0.04045f) ? p : c * (1.0f/12.92f);
}
__device__ __forceinline__ float lab_f(float t){
    float cb = fpow_(t, 1.0f/3.0f);
    return (t > 0.008856f) ? cb : fmaf(7.787f, t, 16.0f/116.0f);
}

__device__ __forceinline__ void rgb2lab(float r, float g, float b,
                                        float& L, float& A, float& Bv){
    float lr = srgb_lin(r), lg = srgb_lin(g), lb = srgb_lin(b);
    float xn = fmaf(0.4124564f, lr, fmaf(0.3575761f, lg, 0.1804375f*lb)) * (1.0f/0.95047f);
    float yn = fmaf(0.2126729f, lr, fmaf(0.7151522f, lg, 0.072175f *lb));
    float zn = fmaf(0.0193339f, lr, fmaf(0.119192f , lg, 0.9503041f*lb)) * (1.0f/1.08883f);
    float fx = lab_f(xn), fy = lab_f(yn), fz = lab_f(zn);
    L  = fmaf(116.0f, fy, -16.0f);
    A  = 500.0f * (fx - fy);
    Bv = 200.0f * (fy - fz);
}

// atan2(y,x) mod 2pi, in [0, 2pi). Polynomial minimax atan on [0,1], |err|~1e-6 rad.
__device__ __forceinline__ float fast_atan2_2pi(float y, float x){
    float ax = fabsf(x), ay = fabsf(y);
    float mx = fmaxf(ax, ay), mn = fminf(ax, ay);
    float t = mn * frcp_(fmaxf(mx, 1e-38f));   // guard 0/0 -> t=0
    float s = t * t;
    float p = -0.01172120f;
    p = fmaf(p, s,  0.05265332f);
    p = fmaf(p, s, -0.11643287f);
    p = fmaf(p, s,  0.19354346f);
    p = fmaf(p, s, -0.33262347f);
    p = fmaf(p, s,  0.99997726f);
    p = p * t;
    float r = (ay > ax) ? (1.57079632679f - p) : p;
    r = (x < 0.0f) ? (3.14159265359f - r) : r;
    r = (y < 0.0f) ? (6.28318530718f - r) : r;   // mod 2pi of the negative branch
    return r;
}

__device__ __forceinline__ float row_loss(float pr, float pg, float pb,
                                          float tr, float tg, float tb){
    const float PI_   = 3.14159265359f;
    const float T2PI  = 6.28318530718f;
    const float P257  = 6103515625.0f;   // 25^7

    float dr = pr - tr, dg = pg - tg, db = pb - tb;
    float mse = (dr*dr + dg*dg + db*db) * (1.0f/3.0f);

    float L1, a1, b1, L2, a2, b2;
    rgb2lab(pr, pg, pb, L1, a1, b1);
    rgb2lab(tr, tg, tb, L2, a2, b2);

    float C1 = fsqrt_(fmaf(a1, a1, b1*b1));
    float C2 = fsqrt_(fmaf(a2, a2, b2*b2));
    float Cav = 0.5f * (C1 + C2);
    float c2 = Cav*Cav;
    float c7 = c2*c2*c2*Cav;
    float G = 0.5f * (1.0f - fsqrt_(c7 * frcp_(c7 + P257)));
    float a1p = a1 * (1.0f + G);
    float a2p = a2 * (1.0f + G);
    float C1p = fsqrt_(fmaf(a1p, a1p, b1*b1));
    float C2p = fsqrt_(fmaf(a2p, a2p, b2*b2));
    float h1p = fast_atan2_2pi(b1, a1p);
    float h2p = fast_atan2_2pi(b2, a2p);

    float dL = L2 - L1;
    float dC = C2p - C1p;
    float dh = h2p - h1p;
    if (fabsf(dh) > PI_) dh = (h2p <= h1p) ? (dh + T2PI) : (dh - T2PI);
    float dH = 2.0f * fsqrt_(C1p * C2p) * __sinf(0.5f * dh);

    float Lav  = 0.5f * (L1 + L2);
    float Cpav = 0.5f * (C1p + C2p);
    float hsum = h1p + h2p;
    float hav = (fabsf(h1p - h2p) > PI_) ? 0.5f*(hsum + T2PI) : 0.5f*hsum;

    float T = 1.0f
            - 0.17f * __cosf(hav - 0.52359877559f)           // pi/6
            + 0.24f * __cosf(2.0f * hav)
            + 0.32f * __cosf(fmaf(3.0f, hav,  0.10471975512f)) // pi/30
            - 0.20f * __cosf(fmaf(4.0f, hav, -1.09955742876f)); // 7pi/20

    float u = fmaf(hav, 57.2957795131f, -275.0f) * 0.04f;    // (deg-275)/25
    float theta = 30.0f * __expf(-u*u);

    float cp2 = Cpav*Cpav;
    float cp7 = cp2*cp2*cp2*Cpav;
    float RC = 2.0f * fsqrt_(cp7 * frcp_(cp7 + P257));
    float RT = -__sinf(2.0f * theta) * RC;

    float Lm = Lav - 50.0f;
    float Lm2 = Lm * Lm;
    float SL = fmaf(0.015f * Lm2, frsq_(20.0f + Lm2), 1.0f);
    float SC = fmaf(0.045f, Cpav, 1.0f);
    float SH = fmaf(0.015f * Cpav, T, 1.0f);

    float t1 = dL * frcp_(SL);
    float t2 = dC * frcp_(SC);
    float t3 = dH * frcp_(SH);
    float arg = fmaf(t1, t1, fmaf(t2, t2, fmaf(t3, t3, RT*t2*t3)));
    float de = fsqrt_(fmaxf(arg, 0.0f));

    return fmaf(0.2f, mse, 0.8f * de);
}

__global__ void __launch_bounds__(TPB)
de_main(const float* __restrict__ pred, const float* __restrict__ tgt,
        float* __restrict__ partials, int B){
    int nvec = B >> 2;                 // groups of 4 rows = 12 floats = 3 float4
    int gid = blockIdx.x * TPB + threadIdx.x;
    int stride = gridDim.x * TPB;
    float acc = 0.0f;

    for (int i = gid; i < nvec; i += stride){
        const float4* p4 = (const float4*)pred + (size_t)i * 3;
        const float4* t4 = (const float4*)tgt  + (size_t)i * 3;
        float4 pA = p4[0], pB = p4[1], pC = p4[2];
        float4 tA = t4[0], tB = t4[1], tC = t4[2];
        acc += row_loss(pA.x, pA.y, pA.z, tA.x, tA.y, tA.z);
        acc += row_loss(pA.w, pB.x, pB.y, tA.w, tB.x, tB.y);
        acc += row_loss(pB.z, pB.w, pC.x, tB.z, tB.w, tC.x);
        acc += row_loss(pC.y, pC.z, pC.w, tC.y, tC.z, tC.w);
    }
    // tail rows (B % 4), at most 3 — handled by first few global threads
    int r = (nvec << 2) + gid;
    if (r < B){
        acc += row_loss(pred[(size_t)r*3], pred[(size_t)r*3+1], pred[(size_t)r*3+2],
                        tgt [(size_t)r*3], tgt [(size_t)r*3+1], tgt [(size_t)r*3+2]);
    }

    __shared__ float sdata[TPB];
    sdata[threadIdx.x] = acc;
    __syncthreads();
    #pragma unroll
    for (int s = TPB/2; s > 0; s >>= 1){
        if (threadIdx.x < s) sdata[threadIdx.x] += sdata[threadIdx.x + s];
        __syncthreads();
    }
    if (threadIdx.x == 0) partials[blockIdx.x] = sdata[0];
}

__global__ void __launch_bounds__(TPB)
de_final(const float* __restrict__ partials, int n, float* __restrict__ out, double invB){
    __shared__ double sd[TPB];
    double acc = 0.0;
    for (int i = threadIdx.x; i < n; i += TPB) acc += (double)partials[i];
    sd[threadIdx.x] = acc;
    __syncthreads();
    #pragma unroll
    for (int s = TPB/2; s > 0; s >>= 1){
        if (threadIdx.x < s) sd[threadIdx.x] += sd[threadIdx.x + s];
        __syncthreads();
    }
    if (threadIdx.x == 0) out[0] = (float)(sd[0] * invB);
}

extern "C" void kernel_launch(void* const* d_in, const int* in_sizes, int n_in,
                              void* d_out, int out_size, void* d_ws, size_t ws_size,
                              hipStream_t stream){
    const float* pred = (const float*)d_in[0];
    const float* tgt  = (const float*)d_in[1];
    int B = in_sizes[0] / 3;

    int nvec = B >> 2;
    int blocks = (nvec + TPB - 1) / TPB;
    if (blocks > MAXBLOCKS) blocks = MAXBLOCKS;
    size_t wcap = ws_size / sizeof(float);
    if (wcap > 0 && (size_t)blocks > wcap) blocks = (int)wcap;
    if (blocks < 1) blocks = 1;

    float* partials = (float*)d_ws;
    de_main <<<blocks, TPB, 0, stream>>>(pred, tgt, partials, B);
    de_final<<<1, TPB, 0, stream>>>(partials, blocks, (float*)d_out, 1.0/(double)B);
}

// Round 2
// 428.031 us; speedup vs baseline: 1.0568x; 1.0568x over previous
//
#include <hip/hip_runtime.h>
#include <math.h>

#define TPB 256
#define MAXBLOCKS 8192

__device__ __forceinline__ float fsqrt_(float x){ return __builtin_amdgcn_sqrtf(x); }
__device__ __forceinline__ float frcp_ (float x){ return __builtin_amdgcn_rcpf(x); }
__device__ __forceinline__ float frsq_ (float x){ return __builtin_amdgcn_rsqf(x); }
__device__ __forceinline__ float flog2_(float x){ return __builtin_amdgcn_logf(x); }   // v_log_f32 (log2)
__device__ __forceinline__ float fexp2_(float x){ return __builtin_amdgcn_exp2f(x); }  // v_exp_f32 (exp2)
// x^y for x>0: exp2(y*log2(x)) — raw trans, no ln2 fixup muls
__device__ __forceinline__ float fpow_(float x, float y){ return fexp2_(y * flog2_(x)); }

__device__ __forceinline__ float srgb_lin(float c){
    float p = fpow_((c + 0.055f) * (1.0f/1.055f), 2.4f);
    return (c > 0.04045f) ? p : c * (1.0f/12.92f);
}
__device__ __forceinline__ float lab_f(float t){
    float cb = fpow_(t, 1.0f/3.0f);
    return (t > 0.008856f) ? cb : fmaf(7.787f, t, 16.0f/116.0f);
}

__device__ __forceinline__ void rgb2lab(float r, float g, float b,
                                        float& L, float& A, float& Bv){
    float lr = srgb_lin(r), lg = srgb_lin(g), lb = srgb_lin(b);
    float xn = fmaf(0.4124564f, lr, fmaf(0.3575761f, lg, 0.1804375f*lb)) * (1.0f/0.95047f);
    float yn = fmaf(0.2126729f, lr, fmaf(0.7151522f, lg, 0.072175f *lb));
    float zn = fmaf(0.0193339f, lr, fmaf(0.119192f , lg, 0.9503041f*lb)) * (1.0f/1.08883f);
    float fx = lab_f(xn), fy = lab_f(yn), fz = lab_f(zn);
    L  = fmaf(116.0f, fy, -16.0f);
    A  = 500.0f * (fx - fy);
    Bv = 200.0f * (fy - fz);
}

// atan2(y,x) mod 2pi in [0, 2pi). Minimax atan on [0,1], |err|~1e-6 rad.
__device__ __forceinline__ float fast_atan2_2pi(float y, float x){
    float ax = fabsf(x), ay = fabsf(y);
    float mx = fmaxf(ax, ay), mn = fminf(ax, ay);
    float t = mn * frcp_(fmaxf(mx, 1e-38f));   // guard 0/0 -> t=0
    float s = t * t;
    float p = -0.01172120f;
    p = fmaf(p, s,  0.05265332f);
    p = fmaf(p, s, -0.11643287f);
    p = fmaf(p, s,  0.19354346f);
    p = fmaf(p, s, -0.33262347f);
    p = fmaf(p, s,  0.99997726f);
    p = p * t;
    float r = (ay > ax) ? (1.57079632679f - p) : p;
    r = (x < 0.0f) ? (3.14159265359f - r) : r;
    r = (y < 0.0f) ? (6.28318530718f - r) : r;
    return r;
}

__device__ __forceinline__ float row_loss(float pr, float pg, float pb,
                                          float tr, float tg, float tb){
    const float P257 = 6103515625.0f;   // 25^7

    float dr = pr - tr, dg = pg - tg, db = pb - tb;
    float mse = (dr*dr + dg*dg + db*db) * (1.0f/3.0f);

    float L1, a1, b1, L2, a2, b2;
    rgb2lab(pr, pg, pb, L1, a1, b1);
    rgb2lab(tr, tg, tb, L2, a2, b2);

    float C1 = fsqrt_(fmaf(a1, a1, b1*b1));
    float C2 = fsqrt_(fmaf(a2, a2, b2*b2));
    float Cav = 0.5f * (C1 + C2);
    float c2v = Cav*Cav;
    float c7 = c2v*c2v*c2v*Cav;
    // (1+G) = 1.5 - 0.5*sqrt(c7/(c7+25^7))
    float gs = fsqrt_(c7 * frcp_(c7 + P257));
    float opG = fmaf(-0.5f, gs, 1.5f);
    float a1p = a1 * opG;
    float a2p = a2 * opG;
    float C1p = fsqrt_(fmaf(a1p, a1p, b1*b1));
    float C2p = fsqrt_(fmaf(a2p, a2p, b2*b2));

    float dL = L2 - L1;
    float dC = C2p - C1p;

    // dH = sign(cross) * sqrt(2*(C1p*C2p - dot))  — exact chord form of
    // 2*sqrt(C1p*C2p)*sin(dh/2) including the +/-2pi wraparound (sign = sign(sin(h2-h1))).
    float prod  = C1p * C2p;
    float dot   = fmaf(a1p, a2p, b1*b2);
    float cross = fmaf(a1p, b2, -(a2p*b1));
    float dH = copysignf(fsqrt_(fmaxf(2.0f*(prod - dot), 0.0f)), cross);

    float Lav  = 0.5f * (L1 + L2);
    float Cpav = 0.5f * (C1p + C2p);

    // h_avg (with wraparound) = direction of the unit-vector sum.
    // v = C2p*(a1p,b1) + C1p*(a2p,b2)  (same direction as u1+u2; no division needed)
    float vx = fmaf(a1p, C2p, a2p*C1p);
    float vy = fmaf(b1 , C2p, b2 *C1p);
    float hav = fast_atan2_2pi(vy, vx);                 // only needed for the theta Gaussian
    float inv = frsq_(fmaxf(fmaf(vx, vx, vy*vy), 1e-30f));
    float ch = vx * inv, sh = vy * inv;                 // cos/sin(h_avg), no trig

    // T via multiple-angle identities (0 transcendentals)
    float cos2 = fmaf(2.0f*ch, ch, -1.0f);
    float sin2 = 2.0f * sh * ch;
    float cos3 = ch * fmaf(2.0f, cos2, -1.0f);
    float sin3 = sh * fmaf(2.0f, cos2,  1.0f);
    float cos4 = fmaf(2.0f*cos2, cos2, -1.0f);
    float sin4 = 2.0f * sin2 * cos2;
    // 1 - .17*cos(h-pi/6) + .24*cos2h + .32*cos(3h+pi/30) - .2*cos(4h-7pi/20)
    float T = 1.0f;
    T = fmaf(-0.147224319f, ch,   T);   // -.17*cos(pi/6)
    T = fmaf(-0.085f,       sh,   T);   // -.17*sin(pi/6)
    T = fmaf( 0.24f,        cos2, T);
    T = fmaf( 0.318247006f, cos3, T);   // .32*cos(pi/30)
    T = fmaf(-0.033449109f, sin3, T);   // .32*sin(pi/30)
    T = fmaf(-0.090798100f, cos4, T);   // -.2*cos(7pi/20)
    T = fmaf(-0.178201305f, sin4, T);   // -.2*sin(7pi/20)

    // theta = 30*exp(-((deg-275)/25)^2); u = hav*(180/pi)*0.04 - 11
    float u = fmaf(hav, 2.29183118f, -11.0f);
    float theta = 30.0f * fexp2_(-1.44269504f * (u*u));

    float cp2 = Cpav*Cpav;
    float cp7 = cp2*cp2*cp2*Cpav;
    float RC = 2.0f * fsqrt_(cp7 * frcp_(cp7 + P257));
    float RT = -__sinf(2.0f * theta) * RC;

    float Lm = Lav - 50.0f;
    float Lm2 = Lm * Lm;
    float SL = fmaf(0.015f * Lm2, frsq_(20.0f + Lm2), 1.0f);
    float SC = fmaf(0.045f, Cpav, 1.0f);
    float SH = fmaf(0.015f * Cpav, T, 1.0f);

    float t1 = dL * frcp_(SL);
    float t2 = dC * frcp_(SC);
    float t3 = dH * frcp_(SH);
    float arg = fmaf(t1, t1, fmaf(t2, t2, fmaf(t3, t3, RT*t2*t3)));
    float de = fsqrt_(fmaxf(arg, 0.0f));

    return fmaf(0.2f, mse, 0.8f * de);
}

__global__ void __launch_bounds__(TPB)
de_main(const float* __restrict__ pred, const float* __restrict__ tgt,
        float* __restrict__ partials, int B){
    int nvec = B >> 2;                 // groups of 4 rows = 12 floats = 3 float4
    int gid = blockIdx.x * TPB + threadIdx.x;
    int stride = gridDim.x * TPB;
    float acc = 0.0f;

    for (int i = gid; i < nvec; i += stride){
        const float4* p4 = (const float4*)pred + (size_t)i * 3;
        const float4* t4 = (const float4*)tgt  + (size_t)i * 3;
        float4 pA = p4[0], pB = p4[1], pC = p4[2];
        float4 tA = t4[0], tB = t4[1], tC = t4[2];
        acc += row_loss(pA.x, pA.y, pA.z, tA.x, tA.y, tA.z);
        acc += row_loss(pA.w, pB.x, pB.y, tA.w, tB.x, tB.y);
        acc += row_loss(pB.z, pB.w, pC.x, tB.z, tB.w, tC.x);
        acc += row_loss(pC.y, pC.z, pC.w, tC.y, tC.z, tC.w);
    }
    int r = (nvec << 2) + gid;          // tail rows (B % 4), at most 3
    if (r < B){
        acc += row_loss(pred[(size_t)r*3], pred[(size_t)r*3+1], pred[(size_t)r*3+2],
                        tgt [(size_t)r*3], tgt [(size_t)r*3+1], tgt [(size_t)r*3+2]);
    }

    __shared__ float sdata[TPB];
    sdata[threadIdx.x] = acc;
    __syncthreads();
    #pragma unroll
    for (int s = TPB/2; s > 0; s >>= 1){
        if (threadIdx.x < s) sdata[threadIdx.x] += sdata[threadIdx.x + s];
        __syncthreads();
    }
    if (threadIdx.x == 0) partials[blockIdx.x] = sdata[0];
}

__global__ void __launch_bounds__(TPB)
de_final(const float* __restrict__ partials, int n, float* __restrict__ out, double invB){
    __shared__ double sd[TPB];
    double acc = 0.0;
    for (int i = threadIdx.x; i < n; i += TPB) acc += (double)partials[i];
    sd[threadIdx.x] = acc;
    __syncthreads();
    #pragma unroll
    for (int s = TPB/2; s > 0; s >>= 1){
        if (threadIdx.x < s) sd[threadIdx.x] += sd[threadIdx.x + s];
        __syncthreads();
    }
    if (threadIdx.x == 0) out[0] = (float)(sd[0] * invB);
}

extern "C" void kernel_launch(void* const* d_in, const int* in_sizes, int n_in,
                              void* d_out, int out_size, void* d_ws, size_t ws_size,
                              hipStream_t stream){
    const float* pred = (const float*)d_in[0];
    const float* tgt  = (const float*)d_in[1];
    int B = in_sizes[0] / 3;

    int nvec = B >> 2;
    int blocks = (nvec + TPB - 1) / TPB;
    if (blocks > MAXBLOCKS) blocks = MAXBLOCKS;
    size_t wcap = ws_size / sizeof(float);
    if (wcap > 0 && (size_t)blocks > wcap) blocks = (int)wcap;
    if (blocks < 1) blocks = 1;

    float* partials = (float*)d_ws;
    de_main <<<blocks, TPB, 0, stream>>>(pred, tgt, partials, B);
    de_final<<<1, TPB, 0, stream>>>(partials, blocks, (float*)d_out, 1.0/(double)B);
}

// Round 3
// 417.102 us; speedup vs baseline: 1.0845x; 1.0262x over previous
//
#include <hip/hip_runtime.h>
#include <math.h>

#define TPB 256
#define MAXBLOCKS 8192

typedef float v4f __attribute__((ext_vector_type(4)));

__device__ __forceinline__ float fsqrt_(float x){ return __builtin_amdgcn_sqrtf(x); }
__device__ __forceinline__ float frcp_ (float x){ return __builtin_amdgcn_rcpf(x); }
__device__ __forceinline__ float frsq_ (float x){ return __builtin_amdgcn_rsqf(x); }
__device__ __forceinline__ float flog2_(float x){ return __builtin_amdgcn_logf(x); }   // v_log_f32
__device__ __forceinline__ float fexp2_(float x){ return __builtin_amdgcn_exp2f(x); }  // v_exp_f32
__device__ __forceinline__ float fsinr_(float x){ return __builtin_amdgcn_sinf(x); }   // v_sin_f32, REVOLUTIONS

__device__ __forceinline__ v4f vs(float x){ return (v4f){x, x, x, x}; }

#define V4APPLY(fn, a) ((v4f){ fn((a).x), fn((a).y), fn((a).z), fn((a).w) })
__device__ __forceinline__ v4f vsqrt(v4f a){ return V4APPLY(fsqrt_, a); }
__device__ __forceinline__ v4f vrcp (v4f a){ return V4APPLY(frcp_ , a); }
__device__ __forceinline__ v4f vrsq (v4f a){ return V4APPLY(frsq_ , a); }
__device__ __forceinline__ v4f vlog2(v4f a){ return V4APPLY(flog2_, a); }
__device__ __forceinline__ v4f vexp2(v4f a){ return V4APPLY(fexp2_, a); }
__device__ __forceinline__ v4f vsinr(v4f a){ return V4APPLY(fsinr_, a); }

#if __has_builtin(__builtin_elementwise_fma)
__device__ __forceinline__ v4f vfma(v4f a, v4f b, v4f c){ return __builtin_elementwise_fma(a,b,c); }
#else
__device__ __forceinline__ v4f vfma(v4f a, v4f b, v4f c){ return a*b + c; }  // ffp-contract
#endif
__device__ __forceinline__ v4f vmax(v4f a, v4f b){ return __builtin_elementwise_max(a,b); }
__device__ __forceinline__ v4f vmin(v4f a, v4f b){ return __builtin_elementwise_min(a,b); }
__device__ __forceinline__ v4f vabs(v4f a){ return __builtin_elementwise_abs(a); }
// per-comp: x > t ? a : b
__device__ __forceinline__ v4f vselgt(v4f x, float t, v4f a, v4f b){
    v4f r;
    r.x = x.x > t ? a.x : b.x;
    r.y = x.y > t ? a.y : b.y;
    r.z = x.z > t ? a.z : b.z;
    r.w = x.w > t ? a.w : b.w;
    return r;
}
__device__ __forceinline__ v4f vcopysign(v4f m, v4f s){
    v4f r;
    r.x = copysignf(m.x, s.x);
    r.y = copysignf(m.y, s.y);
    r.z = copysignf(m.z, s.z);
    r.w = copysignf(m.w, s.w);
    return r;
}

__device__ __forceinline__ v4f srgb_lin(v4f c){
    v4f t = (c + vs(0.055f)) * vs(1.0f/1.055f);
    v4f p = vexp2(vs(2.4f) * vlog2(t));
    return vselgt(c, 0.04045f, p, c * vs(1.0f/12.92f));
}
__device__ __forceinline__ v4f lab_f(v4f t){
    v4f cb = vexp2(vs(1.0f/3.0f) * vlog2(t));
    return vselgt(t, 0.008856f, cb, vfma(vs(7.787f), t, vs(16.0f/116.0f)));
}

// XYZ_REF divides folded into the matrix rows.
__device__ __forceinline__ void rgb2lab(v4f r, v4f g, v4f b, v4f& L, v4f& A, v4f& Bv){
    v4f lr = srgb_lin(r), lg = srgb_lin(g), lb = srgb_lin(b);
    v4f xn = vfma(vs(0.4339499f), lr, vfma(vs(0.3762098f), lg, vs(0.1898414f)*lb));
    v4f yn = vfma(vs(0.2126729f), lr, vfma(vs(0.7151522f), lg, vs(0.0721750f)*lb));
    v4f zn = vfma(vs(0.0177566f), lr, vfma(vs(0.1094680f), lg, vs(0.8727720f)*lb));
    v4f fx = lab_f(xn), fy = lab_f(yn), fz = lab_f(zn);
    L  = vfma(vs(116.0f), fy, vs(-16.0f));
    A  = vs(500.0f) * (fx - fy);
    Bv = vs(200.0f) * (fy - fz);
}

// atan2(y,x) mod 2pi in [0,2pi); minimax atan on [0,1], |err|~1e-6 rad.
__device__ __forceinline__ v4f vatan2_2pi(v4f y, v4f x){
    v4f ax = vabs(x), ay = vabs(y);
    v4f mx = vmax(ax, ay), mn = vmin(ax, ay);
    v4f t = mn * vrcp(vmax(mx, vs(1e-38f)));
    v4f s = t * t;
    v4f p = vs(-0.01172120f);
    p = vfma(p, s, vs( 0.05265332f));
    p = vfma(p, s, vs(-0.11643287f));
    p = vfma(p, s, vs( 0.19354346f));
    p = vfma(p, s, vs(-0.33262347f));
    p = vfma(p, s, vs( 0.99997726f));
    p = p * t;
    v4f r = vselgt(ay - ax, 0.0f, vs(1.57079632679f) - p, p);   // ay>ax
    r = vselgt(vs(0.0f) - x, 0.0f, vs(3.14159265359f) - r, r);  // x<0
    r = vselgt(vs(0.0f) - y, 0.0f, vs(6.28318530718f) - r, r);  // y<0
    return r;
}

// loss for 4 rows at once (packed fp32)
__device__ __forceinline__ v4f row_loss(v4f pr, v4f pg, v4f pb,
                                        v4f tr, v4f tg, v4f tb){
    const float P257 = 6103515625.0f;   // 25^7

    v4f dr = pr - tr, dg = pg - tg, db = pb - tb;
    v4f mse = (dr*dr + dg*dg + db*db) * vs(1.0f/3.0f);

    v4f L1, a1, b1, L2, a2, b2;
    rgb2lab(pr, pg, pb, L1, a1, b1);
    rgb2lab(tr, tg, tb, L2, a2, b2);

    v4f C1 = vsqrt(vfma(a1, a1, b1*b1));
    v4f C2 = vsqrt(vfma(a2, a2, b2*b2));
    v4f Cav = vs(0.5f) * (C1 + C2);
    v4f c2v = Cav*Cav;
    v4f c7 = c2v*c2v*c2v*Cav;
    v4f gs = vsqrt(c7 * vrcp(c7 + vs(P257)));
    v4f opG = vfma(vs(-0.5f), gs, vs(1.5f));      // 1+G
    v4f a1p = a1 * opG;
    v4f a2p = a2 * opG;
    v4f C1p = vsqrt(vfma(a1p, a1p, b1*b1));
    v4f C2p = vsqrt(vfma(a2p, a2p, b2*b2));

    v4f dL = L2 - L1;
    v4f dC = C2p - C1p;

    // chord form of dH (exact incl. wraparound; sign = sign of 2D cross)
    v4f prod  = C1p * C2p;
    v4f dot   = vfma(a1p, a2p, b1*b2);
    v4f cross = vfma(a1p, b2, vs(0.0f) - a2p*b1);
    v4f dH = vcopysign(vsqrt(vmax(vs(2.0f)*(prod - dot), vs(0.0f))), cross);

    v4f Lav  = vs(0.5f) * (L1 + L2);
    v4f Cpav = vs(0.5f) * (C1p + C2p);

    // h_avg direction via vector sum (no wraparound branches)
    v4f vx = vfma(a1p, C2p, a2p*C1p);
    v4f vy = vfma(b1 , C2p, b2 *C1p);
    v4f hav = vatan2_2pi(vy, vx);                    // only for the theta Gaussian
    v4f inv = vrsq(vmax(vfma(vx, vx, vy*vy), vs(1e-30f)));
    v4f ch = vx * inv, sh = vy * inv;                // cos/sin(h_avg)

    // T via multiple-angle identities (0 trans)
    v4f cos2 = vfma(vs(2.0f)*ch, ch, vs(-1.0f));
    v4f sin2 = vs(2.0f) * sh * ch;
    v4f cos3 = ch * vfma(vs(2.0f), cos2, vs(-1.0f));
    v4f sin3 = sh * vfma(vs(2.0f), cos2, vs( 1.0f));
    v4f cos4 = vfma(vs(2.0f)*cos2, cos2, vs(-1.0f));
    v4f sin4 = vs(2.0f) * sin2 * cos2;
    v4f T = vs(1.0f);
    T = vfma(vs(-0.147224319f), ch,   T);
    T = vfma(vs(-0.085f),       sh,   T);
    T = vfma(vs( 0.24f),        cos2, T);
    T = vfma(vs( 0.318247006f), cos3, T);
    T = vfma(vs(-0.033449109f), sin3, T);
    T = vfma(vs(-0.090798100f), cos4, T);
    T = vfma(vs(-0.178201305f), sin4, T);

    // theta = 30*exp(-((deg-275)/25)^2)
    v4f u = vfma(hav, vs(2.29183118f), vs(-11.0f));
    v4f theta = vs(30.0f) * vexp2(vs(-1.44269504f) * (u*u));

    v4f cp2 = Cpav*Cpav;
    v4f cp7 = cp2*cp2*cp2*Cpav;
    v4f RC = vs(2.0f) * vsqrt(cp7 * vrcp(cp7 + vs(P257)));
    // sin(2*theta): v_sin takes revolutions -> 2*theta/(2pi) = theta/pi
    v4f RT = vs(0.0f) - vsinr(theta * vs(0.31830988618f)) * RC;

    v4f Lm = Lav - vs(50.0f);
    v4f Lm2 = Lm * Lm;
    v4f SL = vfma(vs(0.015f) * Lm2, vrsq(vs(20.0f) + Lm2), vs(1.0f));
    v4f SC = vfma(vs(0.045f), Cpav, vs(1.0f));
    v4f SH = vfma(vs(0.015f) * Cpav, T, vs(1.0f));

    v4f t1 = dL * vrcp(SL);
    v4f t2 = dC * vrcp(SC);
    v4f t3 = dH * vrcp(SH);
    v4f arg = vfma(t1, t1, vfma(t2, t2, vfma(t3, t3, RT*t2*t3)));
    v4f de = vsqrt(vmax(arg, vs(0.0f)));

    return vfma(vs(0.2f), mse, vs(0.8f) * de);
}

__global__ void __launch_bounds__(TPB)
de_main(const float* __restrict__ pred, const float* __restrict__ tgt,
        float* __restrict__ partials, int B){
    int nvec = B >> 2;                 // groups of 4 rows = 3 float4
    int gid = blockIdx.x * TPB + threadIdx.x;
    int stride = gridDim.x * TPB;
    v4f acc4 = vs(0.0f);

    for (int i = gid; i < nvec; i += stride){
        const float4* p4 = (const float4*)pred + (size_t)i * 3;
        const float4* t4 = (const float4*)tgt  + (size_t)i * 3;
        float4 pA = p4[0], pB = p4[1], pC = p4[2];
        float4 tA = t4[0], tB = t4[1], tC = t4[2];
        // transpose 4 rows into channel vectors
        v4f pr = (v4f){pA.x, pA.w, pB.z, pC.y};
        v4f pg = (v4f){pA.y, pB.x, pB.w, pC.z};
        v4f pb = (v4f){pA.z, pB.y, pC.x, pC.w};
        v4f qr = (v4f){tA.x, tA.w, tB.z, tC.y};
        v4f qg = (v4f){tA.y, tB.x, tB.w, tC.z};
        v4f qb = (v4f){tA.z, tB.y, tC.x, tC.w};
        acc4 += row_loss(pr, pg, pb, qr, qg, qb);
    }
    float acc = acc4.x + acc4.y + acc4.z + acc4.w;

    int r = (nvec << 2) + gid;          // tail rows (B % 4), at most 3
    if (r < B){
        v4f pr = vs(pred[(size_t)r*3]), pg = vs(pred[(size_t)r*3+1]), pb = vs(pred[(size_t)r*3+2]);
        v4f qr = vs(tgt [(size_t)r*3]), qg = vs(tgt [(size_t)r*3+1]), qb = vs(tgt [(size_t)r*3+2]);
        acc += row_loss(pr, pg, pb, qr, qg, qb).x;
    }

    __shared__ float sdata[TPB];
    sdata[threadIdx.x] = acc;
    __syncthreads();
    #pragma unroll
    for (int s = TPB/2; s > 0; s >>= 1){
        if (threadIdx.x < s) sdata[threadIdx.x] += sdata[threadIdx.x + s];
        __syncthreads();
    }
    if (threadIdx.x == 0) partials[blockIdx.x] = sdata[0];
}

__global__ void __launch_bounds__(TPB)
de_final(const float* __restrict__ partials, int n, float* __restrict__ out, double invB){
    __shared__ double sd[TPB];
    double acc = 0.0;
    for (int i = threadIdx.x; i < n; i += TPB) acc += (double)partials[i];
    sd[threadIdx.x] = acc;
    __syncthreads();
    #pragma unroll
    for (int s = TPB/2; s > 0; s >>= 1){
        if (threadIdx.x < s) sd[threadIdx.x] += sd[threadIdx.x + s];
        __syncthreads();
    }
    if (threadIdx.x == 0) out[0] = (float)(sd[0] * invB);
}

extern "C" void kernel_launch(void* const* d_in, const int* in_sizes, int n_in,
                              void* d_out, int out_size, void* d_ws, size_t ws_size,
                              hipStream_t stream){
    const float* pred = (const float*)d_in[0];
    const float* tgt  = (const float*)d_in[1];
    int B = in_sizes[0] / 3;

    int nvec = B >> 2;
    int blocks = (nvec + TPB - 1) / TPB;
    if (blocks > MAXBLOCKS) blocks = MAXBLOCKS;
    size_t wcap = ws_size / sizeof(float);
    if (wcap > 0 && (size_t)blocks > wcap) blocks = (int)wcap;
    if (blocks < 1) blocks = 1;

    float* partials = (float*)d_ws;
    de_main <<<blocks, TPB, 0, stream>>>(pred, tgt, partials, B);
    de_final<<<1, TPB, 0, stream>>>(partials, blocks, (float*)d_out, 1.0/(double)B);
}